// Round 1
// baseline (424.870 us; speedup 1.0000x reference)
//
#include <hip/hip_runtime.h>

// RoPE2D: x (T=8192, 2, D=4096) fp32 -> out same shape.
// angle(t) = t * 2*pi/10  => only t % 10 matters (10 distinct cos/sin pairs).
// Memory-bound elementwise: float4 vectorized, one thread per 4-element pair.

#define THETA_D 0.62831853071795864769252867665590  // 2*pi/10

__global__ __launch_bounds__(256) void rope2d_kernel(
    const float4* __restrict__ x, float4* __restrict__ out, int total) {
    int idx = blockIdx.x * blockDim.x + threadIdx.x;
    if (idx >= total) return;

    int t = idx >> 10;        // row index (D/4 = 1024 float4 per half-row)
    int j = idx & 1023;       // float4 column within the row half

    int k = t % 10;           // angle mod 2*pi depends only on t % 10
    float angle = (float)k * (float)THETA_D;
    float s, c;
    sincosf(angle, &s, &c);

    int base = t * 2048;      // 2*4096/4 float4 per t
    const float4 a = x[base + j];           // x[t, 0, 4j..4j+3]
    const float4 b = x[base + 1024 + j];    // x[t, 1, 4j..4j+3]

    float4 o0, o1;
    o0.x = c * a.x - s * b.x;  o1.x = s * a.x + c * b.x;
    o0.y = c * a.y - s * b.y;  o1.y = s * a.y + c * b.y;
    o0.z = c * a.z - s * b.z;  o1.z = s * a.z + c * b.z;
    o0.w = c * a.w - s * b.w;  o1.w = s * a.w + c * b.w;

    out[base + j]        = o0;
    out[base + 1024 + j] = o1;
}

extern "C" void kernel_launch(void* const* d_in, const int* in_sizes, int n_in,
                              void* d_out, int out_size, void* d_ws, size_t ws_size,
                              hipStream_t stream) {
    const float4* x = (const float4*)d_in[0];
    float4* out = (float4*)d_out;

    // total float4-pairs = T * (D/4) = 8192 * 1024
    const int total = (out_size / 2) / 4;   // out_size = T*2*D elements
    const int block = 256;
    const int grid = (total + block - 1) / block;

    rope2d_kernel<<<grid, block, 0, stream>>>(x, out, total);
}